// Round 1
// baseline (49.493 us; speedup 1.0000x reference)
//
#include <hip/hip_runtime.h>

// Mixer: out(B,16,896) = concat[ single(256) | up-mean bcast(256) | down-mean bcast(256)
//                              | pair_up(64) | pair_down(64) ]
// pairwise layout: 240 off-diagonal pairs (row-major, diagonal skipped) + 16 self entries.
// pair index of (e,j), j!=e:  p = e*15 + (j<e ? j : j-1);  self entry of e: p = 240+e.
// Masked sum for (e,spin) = sum over j in spin-window [8*spin, 8*spin+8) of
//   pairwise[p(e,j)] with the diagonal j==e replaced by the self entry 240+e
// (j==e occurs exactly when e's spin matches the window), then / 8.

constexpr int N_EL  = 16;
constexpr int FS    = 256;   // single features
constexpr int FP    = 64;    // pair features
constexpr int FO    = 896;   // output features = 3*256 + 2*64
constexpr int NPAIR = 256;

__device__ __forceinline__ float4 f4add(float4 a, float4 b) {
    return make_float4(a.x + b.x, a.y + b.y, a.z + b.z, a.w + b.w);
}
__device__ __forceinline__ float4 f4scale(float4 a, float s) {
    return make_float4(a.x * s, a.y * s, a.z * s, a.w * s);
}

__global__ __launch_bounds__(256) void mixer_kernel(
    const float* __restrict__ sng,   // (B, 16, 256)
    const float* __restrict__ pw,    // (B, 256, 64)
    float* __restrict__ out)         // (B, 16, 896)
{
    const int b   = blockIdx.x;
    const int tid = threadIdx.x;

    const float* sb = sng + (size_t)b * (N_EL * FS);
    const float* pb = pw  + (size_t)b * (NPAIR * FP);
    float*       ob = out + (size_t)b * (N_EL * FO);

    __shared__ float4 red[4][64];   // 4 KB: per-quadrant partial sums

    // ---------------- Phase A: single echo + spin-mean broadcasts ----------------
    const int f4 = tid & 63;   // float4 column: features [4*f4, 4*f4+4)
    const int g  = tid >> 6;   // electron quadrant: e in [4g, 4g+4)

    float4 s[4];
    float4 ps = make_float4(0.f, 0.f, 0.f, 0.f);
    #pragma unroll
    for (int i = 0; i < 4; ++i) {
        s[i] = *(const float4*)(sb + (g * 4 + i) * FS + f4 * 4);
        ps = f4add(ps, s[i]);
    }
    red[g][f4] = ps;
    __syncthreads();

    const float4 su = f4scale(f4add(red[0][f4], red[1][f4]), 0.125f); // mean over e 0..7
    const float4 sd = f4scale(f4add(red[2][f4], red[3][f4]), 0.125f); // mean over e 8..15

    #pragma unroll
    for (int i = 0; i < 4; ++i) {
        const int e = g * 4 + i;
        float* orow = ob + e * FO;
        *(float4*)(orow +       f4 * 4) = s[i];
        *(float4*)(orow + 256 + f4 * 4) = su;
        *(float4*)(orow + 512 + f4 * 4) = sd;
    }

    // ---------------- Phase B: masked pairwise segment-sums ----------------
    // 32 tasks = (spin, e); 16 lanes (float4) per task; 16 tasks per pass.
    const int lane16 = tid & 15;
    const int tgrp   = tid >> 4;   // 0..15

    #pragma unroll
    for (int iter = 0; iter < 2; ++iter) {
        const int task  = iter * 16 + tgrp;   // 0..31
        const int e     = task & 15;
        const int spin  = task >> 4;          // 0 = up window, 1 = down window
        const int jbase = spin * 8;

        float4 acc = make_float4(0.f, 0.f, 0.f, 0.f);
        #pragma unroll
        for (int j = 0; j < 8; ++j) {
            const int jj  = jbase + j;
            const int row = (jj == e) ? (240 + e)
                                      : (e * 15 + (jj < e ? jj : jj - 1));
            acc = f4add(acc, *(const float4*)(pb + row * FP + lane16 * 4));
        }
        *(float4*)(ob + e * FO + 768 + spin * 64 + lane16 * 4) = f4scale(acc, 0.125f);
    }
}

extern "C" void kernel_launch(void* const* d_in, const int* in_sizes, int n_in,
                              void* d_out, int out_size, void* d_ws, size_t ws_size,
                              hipStream_t stream) {
    const float* sng = (const float*)d_in[0];   // (B,16,256) f32
    const float* pw  = (const float*)d_in[1];   // (B,256,64) f32
    float* out = (float*)d_out;                 // (B,16,896) f32

    const int B = in_sizes[0] / (N_EL * FS);    // 2048
    mixer_kernel<<<B, 256, 0, stream>>>(sng, pw, out);
}

// Round 3
// 46.542 us; speedup vs baseline: 1.0634x; 1.0634x over previous
//
#include <hip/hip_runtime.h>

// Mixer: out(B,16,896) = concat[ single(256) | up-mean bcast(256) | down-mean bcast(256)
//                              | pair_up(64) | pair_down(64) ]
// pairwise layout: 240 off-diagonal pairs (row-major, diagonal skipped) + 16 self entries.
// pair index of (e,j), j!=e:  p = e*15 + (j<e ? j : j-1);  self entry of e: p = 240+e.
// Masked sum for (e,spin) = sum over j in spin-window [8*spin, 8*spin+8) of
//   pairwise[p(e,j)] with the diagonal j==e replaced by the self entry 240+e,
// then / 8.
//
// R3: nontemporal output stores via native vector type (HIP float4 struct is
// rejected by the builtin). Goal: 117 MB write stream bypasses L3 so the
// 168 MB input set stays cache-resident between replays.

constexpr int N_EL  = 16;
constexpr int FS    = 256;   // single features
constexpr int FP    = 64;    // pair features
constexpr int FO    = 896;   // output features = 3*256 + 2*64
constexpr int NPAIR = 256;

typedef float vfloat4 __attribute__((ext_vector_type(4)));

__device__ __forceinline__ float4 f4add(float4 a, float4 b) {
    return make_float4(a.x + b.x, a.y + b.y, a.z + b.z, a.w + b.w);
}
__device__ __forceinline__ float4 f4scale(float4 a, float s) {
    return make_float4(a.x * s, a.y * s, a.z * s, a.w * s);
}
__device__ __forceinline__ void nt_store(float* p, float4 v) {
    vfloat4 nv;
    nv.x = v.x; nv.y = v.y; nv.z = v.z; nv.w = v.w;
    __builtin_nontemporal_store(nv, (vfloat4*)p);
}

__global__ __launch_bounds__(256) void mixer_kernel(
    const float* __restrict__ sng,   // (B, 16, 256)
    const float* __restrict__ pw,    // (B, 256, 64)
    float* __restrict__ out)         // (B, 16, 896)
{
    const int b   = blockIdx.x;
    const int tid = threadIdx.x;

    const float* sb = sng + (size_t)b * (N_EL * FS);
    const float* pb = pw  + (size_t)b * (NPAIR * FP);
    float*       ob = out + (size_t)b * (N_EL * FO);

    __shared__ float4 red[4][64];   // 4 KB: per-quadrant partial sums

    // ---------------- Phase A: single echo + spin-mean broadcasts ----------------
    const int f4 = tid & 63;   // float4 column: features [4*f4, 4*f4+4)
    const int g  = tid >> 6;   // electron quadrant: e in [4g, 4g+4)

    float4 s[4];
    float4 ps = make_float4(0.f, 0.f, 0.f, 0.f);
    #pragma unroll
    for (int i = 0; i < 4; ++i) {
        s[i] = *(const float4*)(sb + (g * 4 + i) * FS + f4 * 4);
        ps = f4add(ps, s[i]);
    }
    red[g][f4] = ps;
    __syncthreads();

    const float4 su = f4scale(f4add(red[0][f4], red[1][f4]), 0.125f); // mean over e 0..7
    const float4 sd = f4scale(f4add(red[2][f4], red[3][f4]), 0.125f); // mean over e 8..15

    #pragma unroll
    for (int i = 0; i < 4; ++i) {
        const int e = g * 4 + i;
        float* orow = ob + e * FO;
        nt_store(orow +       f4 * 4, s[i]);
        nt_store(orow + 256 + f4 * 4, su);
        nt_store(orow + 512 + f4 * 4, sd);
    }

    // ---------------- Phase B: masked pairwise segment-sums ----------------
    // 32 tasks = (spin, e); 16 lanes (float4) per task; 16 tasks per pass.
    const int lane16 = tid & 15;
    const int tgrp   = tid >> 4;   // 0..15

    #pragma unroll
    for (int iter = 0; iter < 2; ++iter) {
        const int task  = iter * 16 + tgrp;   // 0..31
        const int e     = task & 15;
        const int spin  = task >> 4;          // 0 = up window, 1 = down window
        const int jbase = spin * 8;

        float4 acc = make_float4(0.f, 0.f, 0.f, 0.f);
        #pragma unroll
        for (int j = 0; j < 8; ++j) {
            const int jj  = jbase + j;
            const int row = (jj == e) ? (240 + e)
                                      : (e * 15 + (jj < e ? jj : jj - 1));
            acc = f4add(acc, *(const float4*)(pb + row * FP + lane16 * 4));
        }
        nt_store(ob + e * FO + 768 + spin * 64 + lane16 * 4, f4scale(acc, 0.125f));
    }
}

extern "C" void kernel_launch(void* const* d_in, const int* in_sizes, int n_in,
                              void* d_out, int out_size, void* d_ws, size_t ws_size,
                              hipStream_t stream) {
    const float* sng = (const float*)d_in[0];   // (B,16,256) f32
    const float* pw  = (const float*)d_in[1];   // (B,256,64) f32
    float* out = (float*)d_out;                 // (B,16,896) f32

    const int B = in_sizes[0] / (N_EL * FS);    // 2048
    mixer_kernel<<<B, 256, 0, stream>>>(sng, pw, out);
}